// Round 2
// baseline (9.995 us; speedup 1.0000x reference)
//
#include <hip/hip_runtime.h>
#include <math.h>

#define EMBED 1024

__device__ __forceinline__ float dot4(float4 a, float4 b) {
    return a.x * b.x + a.y * b.y + a.z * b.z + a.w * b.w;
}

__global__ __launch_bounds__(256) void lstm_step_kernel(
    const unsigned int* __restrict__ tok,     // low word of int64 token id
    const float* __restrict__ h_in,           // [EMBED]
    const float* __restrict__ c_in,           // [EMBED]
    const float* __restrict__ embed,          // [VOCAB, EMBED]
    const float* __restrict__ W_ih,           // [4*EMBED, EMBED]
    const float* __restrict__ W_hh,           // [4*EMBED, EMBED]
    const float* __restrict__ b_ih,           // [4*EMBED]
    const float* __restrict__ b_hh,           // [4*EMBED]
    float* __restrict__ out)                  // [2*EMBED]: h_new | c_new
{
    __shared__ float x_s[EMBED];
    __shared__ float h_s[EMBED];
    __shared__ float gate_s[4];

    const int tid  = threadIdx.x;
    const int j    = blockIdx.x;               // output element 0..1023
    const int w    = tid >> 6;                 // wave 0..3 -> gate i,f,g,o
    const int lane = tid & 63;
    const int row  = w * EMBED + j;            // gate row in [0, 4096)

    // ---- Issue ALL weight loads first: independent of the token, 32 KB/block
    // in flight while the token-dependent staging chain resolves. ----
    const float4* wi = (const float4*)(W_ih + (size_t)row * EMBED);
    const float4* wh = (const float4*)(W_hh + (size_t)row * EMBED);
    float4 a0 = wi[lane];
    float4 a1 = wi[lane + 64];
    float4 a2 = wi[lane + 128];
    float4 a3 = wi[lane + 192];
    float4 b0 = wh[lane];
    float4 b1 = wh[lane + 64];
    float4 b2 = wh[lane + 128];
    float4 b3 = wh[lane + 192];

    // Wave-uniform scalar loads (bias, cell state) — also early.
    const float bias  = b_ih[row] + b_hh[row];
    const float c_val = c_in[j];

    // ---- Token-dependent staging of x and h into LDS (overlaps weights). ----
    const unsigned int t = tok[0];
    const float* xrow = embed + (size_t)t * EMBED;
    ((float4*)x_s)[tid] = ((const float4*)xrow)[tid];
    ((float4*)h_s)[tid] = ((const float4*)h_in)[tid];
    __syncthreads();

    const float4* xs4 = (const float4*)x_s;
    const float4* hs4 = (const float4*)h_s;

    float acc;
    acc  = dot4(a0, xs4[lane]);
    acc += dot4(a1, xs4[lane + 64]);
    acc += dot4(a2, xs4[lane + 128]);
    acc += dot4(a3, xs4[lane + 192]);
    acc += dot4(b0, hs4[lane]);
    acc += dot4(b1, hs4[lane + 64]);
    acc += dot4(b2, hs4[lane + 128]);
    acc += dot4(b3, hs4[lane + 192]);

    // 64-lane butterfly reduction
    #pragma unroll
    for (int off = 32; off > 0; off >>= 1)
        acc += __shfl_xor(acc, off);

    if (lane == 0)
        gate_s[w] = acc + bias;
    __syncthreads();

    if (tid == 0) {
        const float gi = gate_s[0];
        const float gf = gate_s[1];
        const float gg = gate_s[2];
        const float go = gate_s[3];
        const float i = 1.f / (1.f + __expf(-gi));
        const float f = 1.f / (1.f + __expf(-gf));
        const float e2g = __expf(2.f * gg);
        const float g = (e2g - 1.f) / (e2g + 1.f);      // tanh
        const float o = 1.f / (1.f + __expf(-go));
        const float c_new = f * c_val + i * g;
        const float e2c = __expf(2.f * c_new);
        const float tc  = (e2c - 1.f) / (e2c + 1.f);    // tanh
        const float h_new = o * tc;
        out[j]         = h_new;   // h_new first (tuple order)
        out[EMBED + j] = c_new;   // then c_new
    }
}

extern "C" void kernel_launch(void* const* d_in, const int* in_sizes, int n_in,
                              void* d_out, int out_size, void* d_ws, size_t ws_size,
                              hipStream_t stream) {
    const unsigned int* tok  = (const unsigned int*)d_in[0]; // int64 low word (LE)
    const float* h_in  = (const float*)d_in[1];
    const float* c_in  = (const float*)d_in[2];
    const float* embed = (const float*)d_in[3];
    const float* W_ih  = (const float*)d_in[4];
    const float* W_hh  = (const float*)d_in[5];
    const float* b_ih  = (const float*)d_in[6];
    const float* b_hh  = (const float*)d_in[7];
    float* out = (float*)d_out;

    lstm_step_kernel<<<EMBED, 256, 0, stream>>>(
        tok, h_in, c_in, embed, W_ih, W_hh, b_ih, b_hh, out);
}

// Round 3
// 9.818 us; speedup vs baseline: 1.0181x; 1.0181x over previous
//
#include <hip/hip_runtime.h>
#include <math.h>

#define EMBED 1024

typedef float f32x4 __attribute__((ext_vector_type(4)));

__device__ __forceinline__ float dot4(f32x4 a, f32x4 b) {
    return a[0] * b[0] + a[1] * b[1] + a[2] * b[2] + a[3] * b[3];
}

// 1024 blocks (one per output j) x 512 threads (8 waves).
// Wave w: gate = w>>1 (i,f,g,o), half = w&1 (0: W_ih·x, 1: W_hh·h).
// Each wave computes one full 1024-length dot (4 float4 loads of weights +
// 4 float4 loads of the operand vector, straight from global — the x/h rows
// are shared by all 8192 waves and stay L2/LLC-hot). No staging barrier.
__global__ __launch_bounds__(512) void lstm_step_kernel(
    const unsigned int* __restrict__ tok,     // low word of int64 token id
    const float* __restrict__ h_in,           // [EMBED]
    const float* __restrict__ c_in,           // [EMBED]
    const float* __restrict__ embed,          // [VOCAB, EMBED]
    const float* __restrict__ W_ih,           // [4*EMBED, EMBED]
    const float* __restrict__ W_hh,           // [4*EMBED, EMBED]
    const float* __restrict__ b_ih,           // [4*EMBED]
    const float* __restrict__ b_hh,           // [4*EMBED]
    float* __restrict__ out)                  // [2*EMBED]: h_new | c_new
{
    __shared__ float part[8];

    const int tid  = threadIdx.x;
    const int j    = blockIdx.x;               // output element 0..1023
    const int w    = tid >> 6;                 // wave 0..7
    const int lane = tid & 63;
    const int gate = w >> 1;                   // 0..3 -> i,f,g,o
    const int half = w & 1;                    // 0: ih, 1: hh
    const int row  = gate * EMBED + j;

    // Weight loads first: 4 KB per wave, independent of everything.
    const float* Wm = half ? W_hh : W_ih;
    const f32x4* wr = (const f32x4*)(Wm + (size_t)row * EMBED);
    f32x4 a0 = wr[lane];
    f32x4 a1 = wr[lane + 64];
    f32x4 a2 = wr[lane + 128];
    f32x4 a3 = wr[lane + 192];

    const float bias  = half ? b_hh[row] : b_ih[row];     // wave-uniform s_load
    const float c_val = (w == 0) ? c_in[j] : 0.f;         // wave-uniform

    // Operand vector: embed row (token-dependent) or h — direct from global.
    const float* vbase;
    if (half) {
        vbase = h_in;
    } else {
        const unsigned int t = tok[0];                    // wave-uniform
        vbase = embed + (size_t)t * EMBED;
    }
    const f32x4* v4 = (const f32x4*)vbase;
    f32x4 b0 = v4[lane];
    f32x4 b1 = v4[lane + 64];
    f32x4 b2 = v4[lane + 128];
    f32x4 b3 = v4[lane + 192];

    float acc = dot4(a0, b0) + dot4(a1, b1) + dot4(a2, b2) + dot4(a3, b3);

    // 64-lane butterfly reduction
    #pragma unroll
    for (int off = 32; off > 0; off >>= 1)
        acc += __shfl_xor(acc, off);

    if (lane == 0)
        part[w] = acc + bias;
    __syncthreads();

    if (tid == 0) {
        const float gi = part[0] + part[1];
        const float gf = part[2] + part[3];
        const float gg = part[4] + part[5];
        const float go = part[6] + part[7];
        const float i = 1.f / (1.f + __expf(-gi));
        const float f = 1.f / (1.f + __expf(-gf));
        const float e2g = __expf(2.f * gg);
        const float g = (e2g - 1.f) / (e2g + 1.f);        // tanh
        const float o = 1.f / (1.f + __expf(-go));
        const float c_new = f * c_val + i * g;
        const float e2c = __expf(2.f * c_new);
        const float tc  = (e2c - 1.f) / (e2c + 1.f);      // tanh
        out[j]         = o * tc;    // h_new (tuple order first)
        out[EMBED + j] = c_new;     // c_new
    }
}

extern "C" void kernel_launch(void* const* d_in, const int* in_sizes, int n_in,
                              void* d_out, int out_size, void* d_ws, size_t ws_size,
                              hipStream_t stream) {
    const unsigned int* tok  = (const unsigned int*)d_in[0]; // int64 low word (LE)
    const float* h_in  = (const float*)d_in[1];
    const float* c_in  = (const float*)d_in[2];
    const float* embed = (const float*)d_in[3];
    const float* W_ih  = (const float*)d_in[4];
    const float* W_hh  = (const float*)d_in[5];
    const float* b_ih  = (const float*)d_in[6];
    const float* b_hh  = (const float*)d_in[7];
    float* out = (float*)d_out;

    lstm_step_kernel<<<EMBED, 512, 0, stream>>>(
        tok, h_in, c_in, embed, W_ih, W_hh, b_ih, b_hh, out);
}

// Round 4
// 9.774 us; speedup vs baseline: 1.0226x; 1.0045x over previous
//
#include <hip/hip_runtime.h>
#include <math.h>

#define EMBED 1024

typedef float f32x4 __attribute__((ext_vector_type(4)));

__device__ __forceinline__ float dot4(f32x4 a, f32x4 b) {
    return a[0] * b[0] + a[1] * b[1] + a[2] * b[2] + a[3] * b[3];
}

// 1024 blocks (one per output j) x 512 threads (8 waves).
// Wave w: gate = w>>1 (i,f,g,o), half = w&1 (0: W_ih·x, 1: W_hh·h).
// Weights are read-once streaming -> nontemporal loads (skip cache fill).
// Operand rows (x = embed[tok], h) are reused by 4096 waves each -> cached.
__global__ __launch_bounds__(512) void lstm_step_kernel(
    const unsigned int* __restrict__ tok,     // low word of int64 token id
    const float* __restrict__ h_in,           // [EMBED]
    const float* __restrict__ c_in,           // [EMBED]
    const float* __restrict__ embed,          // [VOCAB, EMBED]
    const float* __restrict__ W_ih,           // [4*EMBED, EMBED]
    const float* __restrict__ W_hh,           // [4*EMBED, EMBED]
    const float* __restrict__ b_ih,           // [4*EMBED]
    const float* __restrict__ b_hh,           // [4*EMBED]
    float* __restrict__ out)                  // [2*EMBED]: h_new | c_new
{
    __shared__ float part[8];

    const int tid  = threadIdx.x;
    const int j    = blockIdx.x;               // output element 0..1023
    const int w    = tid >> 6;                 // wave 0..7
    const int lane = tid & 63;
    const int gate = w >> 1;                   // 0..3 -> i,f,g,o
    const int half = w & 1;                    // 0: ih, 1: hh
    const int row  = gate * EMBED + j;

    // Weight loads first: 4 KB per wave, independent of everything.
    // Nontemporal: read-once stream, don't pay L2/LLC fill.
    const float* Wm = half ? W_hh : W_ih;
    const f32x4* wr = (const f32x4*)(Wm + (size_t)row * EMBED);
    f32x4 a0 = __builtin_nontemporal_load(wr + lane);
    f32x4 a1 = __builtin_nontemporal_load(wr + lane + 64);
    f32x4 a2 = __builtin_nontemporal_load(wr + lane + 128);
    f32x4 a3 = __builtin_nontemporal_load(wr + lane + 192);

    const float bias  = half ? b_hh[row] : b_ih[row];     // wave-uniform s_load
    const float c_val = (w == 0) ? c_in[j] : 0.f;         // wave-uniform

    // Operand vector: embed row (token-dependent) or h — cached, reused 4096x.
    const float* vbase;
    if (half) {
        vbase = h_in;
    } else {
        const unsigned int t = tok[0];                    // wave-uniform
        vbase = embed + (size_t)t * EMBED;
    }
    const f32x4* v4 = (const f32x4*)vbase;
    f32x4 b0 = v4[lane];
    f32x4 b1 = v4[lane + 64];
    f32x4 b2 = v4[lane + 128];
    f32x4 b3 = v4[lane + 192];

    float acc = dot4(a0, b0) + dot4(a1, b1) + dot4(a2, b2) + dot4(a3, b3);

    // 64-lane butterfly reduction
    #pragma unroll
    for (int off = 32; off > 0; off >>= 1)
        acc += __shfl_xor(acc, off);

    if (lane == 0)
        part[w] = acc + bias;
    __syncthreads();

    if (tid == 0) {
        const float gi = part[0] + part[1];
        const float gf = part[2] + part[3];
        const float gg = part[4] + part[5];
        const float go = part[6] + part[7];
        const float i = 1.f / (1.f + __expf(-gi));
        const float f = 1.f / (1.f + __expf(-gf));
        const float e2g = __expf(2.f * gg);
        const float g = (e2g - 1.f) / (e2g + 1.f);        // tanh
        const float o = 1.f / (1.f + __expf(-go));
        const float c_new = f * c_val + i * g;
        const float e2c = __expf(2.f * c_new);
        const float tc  = (e2c - 1.f) / (e2c + 1.f);      // tanh
        out[j]         = o * tc;    // h_new (tuple order first)
        out[EMBED + j] = c_new;     // c_new
    }
}

extern "C" void kernel_launch(void* const* d_in, const int* in_sizes, int n_in,
                              void* d_out, int out_size, void* d_ws, size_t ws_size,
                              hipStream_t stream) {
    const unsigned int* tok  = (const unsigned int*)d_in[0]; // int64 low word (LE)
    const float* h_in  = (const float*)d_in[1];
    const float* c_in  = (const float*)d_in[2];
    const float* embed = (const float*)d_in[3];
    const float* W_ih  = (const float*)d_in[4];
    const float* W_hh  = (const float*)d_in[5];
    const float* b_ih  = (const float*)d_in[6];
    const float* b_hh  = (const float*)d_in[7];
    float* out = (float*)d_out;

    lstm_step_kernel<<<EMBED, 512, 0, stream>>>(
        tok, h_in, c_in, embed, W_ih, W_hh, b_ih, b_hh, out);
}